// Round 4
// baseline (222.321 us; speedup 1.0000x reference)
//
#include <hip/hip_runtime.h>
#include <math.h>

// Problem constants
constexpr int Bn = 32;
constexpr int Cn = 512;
constexpr int Tn = 1024;
constexpr int KS = 13;

// Tiling
constexpr int CB   = 64;           // channels per block
constexpr int TT   = 64;           // timesteps per chunk
constexpr int NCH  = Tn / TT;      // 16 chunks
constexpr int DSTR = TT + 1;       // LDS row stride (odd -> conflict-free)
constexpr int NSEG = 8;            // conv segments (512 conv threads / 64 cols)
constexpr int SEG  = CB / NSEG;    // 8 output rows per conv thread
constexpr int NL   = SEG + KS - 1; // 20 input rows per conv thread

// 256 blocks (32 b x 8 c-groups) x 576 threads (9 waves/CU).
//   wave 0    : scan-only (lane = channel), spikes packed to a uint64 bitmask
//   waves 1-8 : ping-pong register prefetch of x (chunk k+2), conv chunk k+1,
//               expand+store spike bits of chunk k-1 (coalesced)
// One barrier/iter. All fp32 math uses explicit _rn intrinsics (one rounding
// per numpy op, no FMA) — bit-identical to the validated round-2/3 kernels.
__global__ __launch_bounds__(576, 1)
void snn_fused(const float* __restrict__ x, const float* __restrict__ wp,
               float* __restrict__ out) {
  __shared__ float D[2][CB][DSTR];            // drive tiles (33.3 KB)
  __shared__ unsigned long long Sb[2][CB];    // spike bitmasks (1 KB)

  const int tid = threadIdx.x;
  const int b   = blockIdx.y;
  const int c0  = blockIdx.x * CB;
  const long xbase = (long)b * Cn * Tn;

  // ---- Gaussian weights, numpy float32 bit-emulation (validated) ----
  float kw[KS];
  {
    float w  = wp[0];
    float wc = fminf(fmaxf(w, 1.0f), 10.0f);      // clip(w, 1, 10)
    float sigma = __fadd_rn(5.5f, wc);
    float e[KS];
#pragma unroll
    for (int i = 0; i < KS; ++i) {
      float q = __fdiv_rn((float)(i - 6), sigma);
      float t = __fmul_rn(-0.5f, __fmul_rn(q, q));
      e[i] = (float)exp((double)t);
    }
    // numpy pairwise_sum order for n=13
    float s = __fadd_rn(
        __fadd_rn(__fadd_rn(e[0], e[1]), __fadd_rn(e[2], e[3])),
        __fadd_rn(__fadd_rn(e[4], e[5]), __fadd_rn(e[6], e[7])));
    s = __fadd_rn(s, e[8]);  s = __fadd_rn(s, e[9]);  s = __fadd_rn(s, e[10]);
    s = __fadd_rn(s, e[11]); s = __fadd_rn(s, e[12]);
#pragma unroll
    for (int i = 0; i < KS; ++i) kw[i] = __fdiv_rn(e[i], s);
  }

  const bool scanw = (tid < 64);
  const int  ctid  = tid - 64;          // conv-thread id (waves 1..8)
  const int  col   = ctid & 63;         // t-column within chunk
  const int  cseg  = ctid >> 6;         // 0..7, wave-uniform
  const int  segS  = cseg * SEG;
  const int  cin0  = c0 + segS - 6;     // first input channel for this seg

  float xA[NL], xB[NL];                 // ping-pong prefetch buffers (regs)

  auto load_chunk = [&](int m, float* dst) {
#pragma unroll
    for (int j = 0; j < NL; ++j) {
      const int gc = cin0 + j;
      float v = 0.0f;
      if (gc >= 0 && gc < Cn)           // zero pad; wave-uniform branch
        v = x[xbase + (long)gc * Tn + m * TT + col];
      dst[j] = v;
    }
  };
  auto conv_chunk = [&](const float* xs, int p) {
#pragma unroll
    for (int r = 0; r < SEG; ++r) {
      float acc = __fmul_rn(kw[0], xs[r]);        // ascending, no FMA
#pragma unroll
      for (int i = 1; i < KS; ++i)
        acc = __fadd_rn(acc, __fmul_rn(kw[i], xs[r + i]));
      D[p][segS + r][col] = __fsub_rn(xs[r + 6], acc);   // x - x_mean
    }
  };
  auto store_spikes = [&](int m) {      // expand chunk m's bitmasks, store
    const int t0p = m * TT;
#pragma unroll
    for (int r = 0; r < SEG; ++r) {
      const unsigned long long wb = Sb[m & 1][segS + r]; // LDS broadcast
      const float v = ((wb >> col) & 1ull) ? 1.0f : 0.0f;
      out[xbase + (long)(c0 + segS + r) * Tn + t0p + col] = v;
    }
  };

  // ---------------- prologue: conv chunk 0, prefetch chunk 1 ---------------
  if (!scanw) {
    load_chunk(0, xA);
    load_chunk(1, xB);
    conv_chunk(xA, 0);
  }
  __syncthreads();

  float mem = 0.0f;                     // recurrence state (wave 0)

  for (int k = 0; k < NCH; ++k) {
    if (scanw) {
      // ---- scan chunk k; spikes -> bitmask (off the mem critical chain)
      const int c = tid;
      float (*Dc)[DSTR] = D[k & 1];
      unsigned int lo = 0u, hi = 0u;
      float dvA[16], dvB[16];
#pragma unroll
      for (int j = 0; j < 16; ++j) dvA[j] = Dc[c][j];
#pragma unroll
      for (int g = 0; g < 4; ++g) {
        const float* cur = (g & 1) ? dvB : dvA;
        float*       nxt = (g & 1) ? dvA : dvB;
        if (g < 3) {                    // lookahead: hide lgkm latency
#pragma unroll
          for (int j = 0; j < 16; ++j) nxt[j] = Dc[c][(g + 1) * 16 + j];
        }
#pragma unroll
        for (int j = 0; j < 16; ++j) {
          const int t = g * 16 + j;
          const float rthr = (mem > 0.5f) ? 0.5f : 0.0f;   // reset from OLD mem
          float a  = __fmul_rn(0.95f, mem);
          float s2 = __fadd_rn(a, cur[j]);
          mem = __fsub_rn(s2, rthr);
          const unsigned int bit = (mem > 0.5f) ? 1u : 0u;
          if (t < 32) lo |= bit << t;
          else        hi |= bit << (t - 32);
        }
      }
      Sb[k & 1][c] = ((unsigned long long)hi << 32) | (unsigned long long)lo;
    } else {
      // ---- conv waves: loads first (max cover before barrier drain)
      const bool even = ((k & 1) == 0);
      if (k + 2 < NCH) { if (even) load_chunk(k + 2, xA); else load_chunk(k + 2, xB); }
      if (k > 0) store_spikes(k - 1);
      if (k + 1 < NCH) { if (even) conv_chunk(xB, (k + 1) & 1); else conv_chunk(xA, (k + 1) & 1); }
    }
    __syncthreads();
  }

  // ---------------- epilogue: store chunk 15 spikes ------------------------
  if (!scanw) store_spikes(NCH - 1);
}

extern "C" void kernel_launch(void* const* d_in, const int* in_sizes, int n_in,
                              void* d_out, int out_size, void* d_ws, size_t ws_size,
                              hipStream_t stream) {
  const float* x  = (const float*)d_in[0];
  const float* w  = (const float*)d_in[1];
  float* out      = (float*)d_out;
  dim3 grid(Cn / CB, Bn, 1);
  snn_fused<<<grid, 576, 0, stream>>>(x, w, out);
}

// Round 5
// 137.241 us; speedup vs baseline: 1.6199x; 1.6199x over previous
//
#include <hip/hip_runtime.h>
#include <math.h>

// Problem constants
constexpr int Bn = 32;
constexpr int Cn = 512;
constexpr int Tn = 1024;
constexpr int KS = 13;

// Tiling
constexpr int CB   = 64;           // channels per block
constexpr int TT   = 64;           // timesteps per chunk
constexpr int NCH  = Tn / TT;      // 16 chunks
constexpr int DSTR = TT + 1;       // LDS row stride (odd -> conflict-free)
constexpr int NB   = 4;            // drive-slot ring depth
constexpr int NL   = 34;           // input rows per conv thread (22 + 12 halo)

// 256 blocks (32 b x 8 c-groups) x 256 threads (4 waves), 1 block/CU.
// NO per-chunk __syncthreads: producer-consumer pipeline via LDS atomics.
//   waves 1-3 (producers): prefetch x (regs, r3's proven xp/xn+copy pattern),
//       conv chunk k into D[k%NB], release-increment prod[k%NB]; store spike
//       bitmasks of any chunk the scan has finished (opportunistic, no spin).
//   wave 0 (consumer): acquire-spin prod[slot]==3*round, scan 64 steps with
//       two-named-array LDS lookahead (NO pointer selects -> no scratch),
//       write bitmask to Sb[k] (never reused), release-increment scanProg.
// All fp32 math uses explicit _rn intrinsics (one rounding per numpy op, no
// FMA) — bit-identical to the validated round-2/3 kernels.

#define SCAN16(DV, TB)                                                   \
  _Pragma("unroll")                                                      \
  for (int j = 0; j < 16; ++j) {                                         \
    const float rthr = (mem > 0.5f) ? 0.5f : 0.0f;  /* reset: OLD mem */ \
    float a_  = __fmul_rn(0.95f, mem);                                   \
    float s2_ = __fadd_rn(a_, DV[j]);                                    \
    mem = __fsub_rn(s2_, rthr);                                          \
    const unsigned int bit = (mem > 0.5f) ? 1u : 0u;                     \
    if ((TB) + j < 32) lo |= bit << ((TB) + j);                          \
    else               hi |= bit << ((TB) + j - 32);                     \
  }

__global__ __launch_bounds__(256, 1)
void snn_fused(const float* __restrict__ x, const float* __restrict__ wp,
               float* __restrict__ out) {
  __shared__ float D[NB][CB][DSTR];          // drive slot ring (66.6 KB)
  __shared__ unsigned long long Sb[NCH][CB]; // spike bitmasks, no reuse (8 KB)
  __shared__ unsigned int prod[NB];          // producer counters per slot
  __shared__ unsigned int scanProg;          // chunks fully scanned

  const int tid = threadIdx.x;
  const int b   = blockIdx.y;
  const int c0  = blockIdx.x * CB;
  const long xbase = (long)b * Cn * Tn;

  if (tid < NB) prod[tid] = 0u;
  if (tid == NB) scanProg = 0u;

  // ---- Gaussian weights, numpy float32 bit-emulation (validated) ----
  float kw[KS];
  {
    float w  = wp[0];
    float wc = fminf(fmaxf(w, 1.0f), 10.0f);      // clip(w, 1, 10)
    float sigma = __fadd_rn(5.5f, wc);
    float e[KS];
#pragma unroll
    for (int i = 0; i < KS; ++i) {
      float q = __fdiv_rn((float)(i - 6), sigma);
      float t = __fmul_rn(-0.5f, __fmul_rn(q, q));
      e[i] = (float)exp((double)t);
    }
    // numpy pairwise_sum order for n=13
    float s = __fadd_rn(
        __fadd_rn(__fadd_rn(e[0], e[1]), __fadd_rn(e[2], e[3])),
        __fadd_rn(__fadd_rn(e[4], e[5]), __fadd_rn(e[6], e[7])));
    s = __fadd_rn(s, e[8]);  s = __fadd_rn(s, e[9]);  s = __fadd_rn(s, e[10]);
    s = __fadd_rn(s, e[11]); s = __fadd_rn(s, e[12]);
#pragma unroll
    for (int i = 0; i < KS; ++i) kw[i] = __fdiv_rn(e[i], s);
  }

  __syncthreads();   // once: flags zeroed

  if (tid < 64) {
    // ======================= scan wave (consumer) =======================
    const int c = tid;
    float mem = 0.0f;
    for (int k = 0; k < NCH; ++k) {
      const int slot = k & (NB - 1);
      const unsigned need = 3u * ((unsigned)(k / NB) + 1u);
      while (__hip_atomic_load(&prod[slot], __ATOMIC_ACQUIRE,
                               __HIP_MEMORY_SCOPE_WORKGROUP) < need) {}
      const float* Dc = &D[slot][c][0];     // LDS row (2-way alias: free)
      unsigned int lo = 0u, hi = 0u;
      float dvA[16], dvB[16];               // named arrays, const idx only
#pragma unroll
      for (int j = 0; j < 16; ++j) dvA[j] = Dc[j];
#pragma unroll
      for (int j = 0; j < 16; ++j) dvB[j] = Dc[16 + j];   // lookahead g=1
      SCAN16(dvA, 0)
#pragma unroll
      for (int j = 0; j < 16; ++j) dvA[j] = Dc[32 + j];   // lookahead g=2
      SCAN16(dvB, 16)
#pragma unroll
      for (int j = 0; j < 16; ++j) dvB[j] = Dc[48 + j];   // lookahead g=3
      SCAN16(dvA, 32)
      SCAN16(dvB, 48)
      Sb[k][c] = ((unsigned long long)hi << 32) | (unsigned long long)lo;
      if (tid == 0)
        __hip_atomic_fetch_add(&scanProg, 1u, __ATOMIC_RELEASE,
                               __HIP_MEMORY_SCOPE_WORKGROUP);
    }
  } else {
    // ===================== conv waves (producers) =======================
    const int ctid = tid - 64;
    const int col  = ctid & 63;               // t-column (lane)
    const int segS = (ctid >> 6) * 21;        // 0, 21, 42 (rows 22 each)
    const int cin0 = c0 + segS - 6;

    float xp[NL], xn[NL];                     // r3's proven scratch-free pair

    auto load_chunk = [&](int m, float* dst) {
#pragma unroll
      for (int j = 0; j < NL; ++j) {
        const int gc = cin0 + j;
        float v = 0.0f;
        if (gc >= 0 && gc < Cn)               // zero pad; wave-uniform branch
          v = x[xbase + (long)gc * Tn + m * TT + col];
        dst[j] = v;
      }
    };
    auto conv_chunk = [&](const float* xs, int p) {
#pragma unroll
      for (int r = 0; r < 22; ++r) {
        float acc = __fmul_rn(kw[0], xs[r]);  // ascending, no FMA
#pragma unroll
        for (int i = 1; i < KS; ++i)
          acc = __fadd_rn(acc, __fmul_rn(kw[i], xs[r + i]));
        D[p][segS + r][col] = __fsub_rn(xs[r + 6], acc);  // x - x_mean
      }
    };
    auto store_spikes = [&](int m) {          // expand bitmask, coalesced
      const int t0p = m * TT;
#pragma unroll
      for (int r = 0; r < 22; ++r) {
        const unsigned long long wb = Sb[m][segS + r];    // LDS broadcast
        const float v = ((wb >> col) & 1ull) ? 1.0f : 0.0f;
        out[xbase + (long)(c0 + segS + r) * Tn + t0p + col] = v;
      }
    };

    load_chunk(0, xp);
    int nextStore = 0;
    for (int k = 0; k < NCH; ++k) {
      if (k + 1 < NCH) load_chunk(k + 1, xn); // issue loads first
      if (k >= NB) {                          // wait for slot to be consumed
        const unsigned need = (unsigned)(k - NB + 1);
        while (__hip_atomic_load(&scanProg, __ATOMIC_ACQUIRE,
                                 __HIP_MEMORY_SCOPE_WORKGROUP) < need) {}
      }
      conv_chunk(xp, k & (NB - 1));
      if (col == 0)
        __hip_atomic_fetch_add(&prod[k & (NB - 1)], 1u, __ATOMIC_RELEASE,
                               __HIP_MEMORY_SCOPE_WORKGROUP);
      if (k + 1 < NCH) {
#pragma unroll
        for (int j = 0; j < NL; ++j) xp[j] = xn[j];
      }
      // opportunistic spike stores (no spin: bounded by snapshot)
      const unsigned sp = __hip_atomic_load(&scanProg, __ATOMIC_ACQUIRE,
                                            __HIP_MEMORY_SCOPE_WORKGROUP);
      while (nextStore < (int)sp) { store_spikes(nextStore); ++nextStore; }
    }
    // tail drain
    while (nextStore < NCH) {
      while (__hip_atomic_load(&scanProg, __ATOMIC_ACQUIRE,
                               __HIP_MEMORY_SCOPE_WORKGROUP)
             < (unsigned)(nextStore + 1)) {}
      store_spikes(nextStore); ++nextStore;
    }
  }
}

extern "C" void kernel_launch(void* const* d_in, const int* in_sizes, int n_in,
                              void* d_out, int out_size, void* d_ws, size_t ws_size,
                              hipStream_t stream) {
  const float* x  = (const float*)d_in[0];
  const float* w  = (const float*)d_in[1];
  float* out      = (float*)d_out;
  dim3 grid(Cn / CB, Bn, 1);
  snn_fused<<<grid, 256, 0, stream>>>(x, w, out);
}

// Round 6
// 132.321 us; speedup vs baseline: 1.6802x; 1.0372x over previous
//
#include <hip/hip_runtime.h>
#include <math.h>

// Problem constants
constexpr int Bn = 32;
constexpr int Cn = 512;
constexpr int Tn = 1024;
constexpr int KS = 13;

// Tiling
constexpr int CB   = 64;           // channels per block
constexpr int TT   = 64;           // timesteps per chunk
constexpr int NCH  = Tn / TT;      // 16 chunks
constexpr int DSTR = TT + 1;       // LDS row stride (odd -> conflict-free)
constexpr int NB   = 4;            // drive-slot ring depth
constexpr int NL   = 34;           // input rows per conv thread (22 + 12 halo)

// 256 blocks (32 b x 8 c-groups) x 320 threads (5 waves), 1 block/CU.
// Producer-consumer pipeline via LDS atomics (validated in r5), but with the
// global-store stream ISOLATED in wave 4: on CDNA stores count in vmcnt, so
// any wave that both stores and then waits vmcnt (release fence / prefetch
// copy / barrier) serializes on store-acks under write backpressure. Here:
//   wave 0    (scan) : LDS only. Consumes D[k%NB], packs spikes to Sb[k].
//   waves 1-3 (conv) : global LOADS + LDS writes only. Ping-pong reg prefetch.
//   wave 4   (store) : LDS reads + global STORES only — never waits vmcnt.
// All fp32 math uses explicit _rn intrinsics (one rounding per numpy op, no
// FMA) — bit-identical to the validated round-2/3/5 kernels.

#define SCAN16(DV, TB)                                                   \
  _Pragma("unroll")                                                      \
  for (int j = 0; j < 16; ++j) {                                         \
    const float rthr = (mem > 0.5f) ? 0.5f : 0.0f;  /* reset: OLD mem */ \
    float a_  = __fmul_rn(0.95f, mem);                                   \
    float s2_ = __fadd_rn(a_, DV[j]);                                    \
    mem = __fsub_rn(s2_, rthr);                                          \
    const unsigned int bit = (mem > 0.5f) ? 1u : 0u;                     \
    if ((TB) + j < 32) lo |= bit << ((TB) + j);                          \
    else               hi |= bit << ((TB) + j - 32);                     \
  }

__global__ __launch_bounds__(320, 1)
void snn_fused(const float* __restrict__ x, const float* __restrict__ wp,
               float* __restrict__ out) {
  __shared__ float D[NB][CB][DSTR];          // drive slot ring (66.6 KB)
  __shared__ unsigned long long Sb[NCH][CB]; // spike bitmasks, no reuse (8 KB)
  __shared__ unsigned int prod[NB];          // producer counters per slot
  __shared__ unsigned int scanProg;          // chunks fully scanned

  const int tid = threadIdx.x;
  const int b   = blockIdx.y;
  const int c0  = blockIdx.x * CB;
  const long xbase = (long)b * Cn * Tn;

  if (tid < NB) prod[tid] = 0u;
  if (tid == NB) scanProg = 0u;

  // ---- Gaussian weights, numpy float32 bit-emulation (validated) ----
  float kw[KS];
  {
    float w  = wp[0];
    float wc = fminf(fmaxf(w, 1.0f), 10.0f);      // clip(w, 1, 10)
    float sigma = __fadd_rn(5.5f, wc);
    float e[KS];
#pragma unroll
    for (int i = 0; i < KS; ++i) {
      float q = __fdiv_rn((float)(i - 6), sigma);
      float t = __fmul_rn(-0.5f, __fmul_rn(q, q));
      e[i] = (float)exp((double)t);
    }
    // numpy pairwise_sum order for n=13
    float s = __fadd_rn(
        __fadd_rn(__fadd_rn(e[0], e[1]), __fadd_rn(e[2], e[3])),
        __fadd_rn(__fadd_rn(e[4], e[5]), __fadd_rn(e[6], e[7])));
    s = __fadd_rn(s, e[8]);  s = __fadd_rn(s, e[9]);  s = __fadd_rn(s, e[10]);
    s = __fadd_rn(s, e[11]); s = __fadd_rn(s, e[12]);
#pragma unroll
    for (int i = 0; i < KS; ++i) kw[i] = __fdiv_rn(e[i], s);
  }

  __syncthreads();   // once: flags zeroed

  if (tid < 64) {
    // ======================= scan wave (consumer, LDS-only) =============
    const int c = tid;
    float mem = 0.0f;
    for (int k = 0; k < NCH; ++k) {
      const int slot = k & (NB - 1);
      const unsigned need = 3u * ((unsigned)(k / NB) + 1u);
      while (__hip_atomic_load(&prod[slot], __ATOMIC_ACQUIRE,
                               __HIP_MEMORY_SCOPE_WORKGROUP) < need) {}
      const float* Dc = &D[slot][c][0];     // LDS row (2-way alias: free)
      unsigned int lo = 0u, hi = 0u;
      float dvA[16], dvB[16];               // named arrays, const idx only
#pragma unroll
      for (int j = 0; j < 16; ++j) dvA[j] = Dc[j];
#pragma unroll
      for (int j = 0; j < 16; ++j) dvB[j] = Dc[16 + j];   // lookahead g=1
      SCAN16(dvA, 0)
#pragma unroll
      for (int j = 0; j < 16; ++j) dvA[j] = Dc[32 + j];   // lookahead g=2
      SCAN16(dvB, 16)
#pragma unroll
      for (int j = 0; j < 16; ++j) dvB[j] = Dc[48 + j];   // lookahead g=3
      SCAN16(dvA, 32)
      SCAN16(dvB, 48)
      Sb[k][c] = ((unsigned long long)hi << 32) | (unsigned long long)lo;
      if (tid == 0)
        __hip_atomic_fetch_add(&scanProg, 1u, __ATOMIC_RELEASE,
                               __HIP_MEMORY_SCOPE_WORKGROUP);
    }
  } else if (tid < 256) {
    // ============== conv waves (producers, loads + LDS only) ============
    const int ctid = tid - 64;
    const int col  = ctid & 63;               // t-column (lane)
    const int segS = (ctid >> 6) * 21;        // 0, 21, 42 (rows 22 each)
    const int cin0 = c0 + segS - 6;

    float xp[NL], xn[NL];                     // proven scratch-free pair

    auto load_chunk = [&](int m, float* dst) {
#pragma unroll
      for (int j = 0; j < NL; ++j) {
        const int gc = cin0 + j;
        float v = 0.0f;
        if (gc >= 0 && gc < Cn)               // zero pad; wave-uniform branch
          v = x[xbase + (long)gc * Tn + m * TT + col];
        dst[j] = v;
      }
    };
    auto conv_chunk = [&](const float* xs, int p) {
#pragma unroll
      for (int r = 0; r < 22; ++r) {
        float acc = __fmul_rn(kw[0], xs[r]);  // ascending, no FMA
#pragma unroll
        for (int i = 1; i < KS; ++i)
          acc = __fadd_rn(acc, __fmul_rn(kw[i], xs[r + i]));
        D[p][segS + r][col] = __fsub_rn(xs[r + 6], acc);  // x - x_mean
      }
    };

    load_chunk(0, xp);
    for (int k = 0; k < NCH; ++k) {
      if (k + 1 < NCH) load_chunk(k + 1, xn); // issue loads first
      if (k >= NB) {                          // wait for slot to be consumed
        const unsigned need = (unsigned)(k - NB + 1);
        while (__hip_atomic_load(&scanProg, __ATOMIC_ACQUIRE,
                                 __HIP_MEMORY_SCOPE_WORKGROUP) < need) {}
      }
      conv_chunk(xp, k & (NB - 1));
      if (col == 0)
        __hip_atomic_fetch_add(&prod[k & (NB - 1)], 1u, __ATOMIC_RELEASE,
                               __HIP_MEMORY_SCOPE_WORKGROUP);
      if (k + 1 < NCH) {
#pragma unroll
        for (int j = 0; j < NL; ++j) xp[j] = xn[j];
      }
    }
  } else {
    // ====== store wave (LDS reads + global stores, NEVER waits vmcnt) ===
    const int col = tid & 63;                 // t-column (lane)
    for (int k = 0; k < NCH; ++k) {
      while (__hip_atomic_load(&scanProg, __ATOMIC_ACQUIRE,
                               __HIP_MEMORY_SCOPE_WORKGROUP)
             < (unsigned)(k + 1)) {}
      const int t0p = k * TT;
#pragma unroll 8
      for (int r = 0; r < CB; ++r) {
        const unsigned long long wb = Sb[k][r];          // LDS broadcast
        const float v = ((wb >> col) & 1ull) ? 1.0f : 0.0f;
        out[xbase + (long)(c0 + r) * Tn + t0p + col] = v; // fire & forget
      }
    }
  }
}

extern "C" void kernel_launch(void* const* d_in, const int* in_sizes, int n_in,
                              void* d_out, int out_size, void* d_ws, size_t ws_size,
                              hipStream_t stream) {
  const float* x  = (const float*)d_in[0];
  const float* w  = (const float*)d_in[1];
  float* out      = (float*)d_out;
  dim3 grid(Cn / CB, Bn, 1);
  snn_fused<<<grid, 320, 0, stream>>>(x, w, out);
}